// Round 4
// baseline (510.295 us; speedup 1.0000x reference)
//
#include <hip/hip_runtime.h>
#include <hip/hip_bf16.h>

#define NN 100000
#define NE 1600000
constexpr int NBUK = (NN + 255) / 256;      // 391 dst buckets of 256 nodes
constexpr int CH   = 4096;                  // edges per chunk
constexpr int EPT  = CH / 256;              // 16 edges per thread
constexpr int NCHK = (NE + CH - 1) / CH;    // 391 chunks
constexpr int LCNT = NBUK * NCHK;           // 152,881 counters
constexpr int SCB  = (LCNT + 1023) / 1024;  // 150 scan blocks

// ---------------- edge dtype detection ----------------
__global__ void k_detect_i64(const unsigned* __restrict__ ei, int* __restrict__ flag) {
    __shared__ int any_nz;
    if (threadIdx.x == 0) any_nz = 0;
    __syncthreads();
    int nz = 0;
    for (int i = threadIdx.x; i < 2048; i += 256)
        if (ei[2 * i + 1] != 0u) nz = 1;
    if (nz) atomicExch(&any_nz, 1);
    __syncthreads();
    if (threadIdx.x == 0) *flag = (any_nz == 0) ? 1 : 0;
}

__device__ __forceinline__ int edge_at(const void* ei, int is64, long long idx) {
    if (is64) return (int)((const long long*)ei)[idx];
    return ((const int*)ei)[idx];
}

// ---------------- CSR build: pass 1, per-chunk LDS bucket histogram ----------------
__global__ __launch_bounds__(256) void k_count(const void* __restrict__ ei,
                                               const int* __restrict__ flag,
                                               int* __restrict__ counts) {
    __shared__ int cnt[NBUK];
    const int t = threadIdx.x, blk = blockIdx.x;
    for (int i = t; i < NBUK; i += 256) cnt[i] = 0;
    __syncthreads();
    const int is64 = *flag;
    const int e0 = blk * CH;
    const int elim = min(NE, e0 + CH);
#pragma unroll
    for (int j = 0; j < EPT; j++) {
        int e = e0 + j * 256 + t;
        if (e < elim) {
            int s = edge_at(ei, is64, e);
            int d = edge_at(ei, is64, (long long)NE + e);
            if ((unsigned)s < NN && (unsigned)d < NN) atomicAdd(&cnt[d >> 8], 1);
        }
    }
    __syncthreads();
    for (int i = t; i < NBUK; i += 256) counts[(size_t)i * NCHK + blk] = cnt[i];
}

// ---------------- exclusive scan of counts[LCNT] (in place) ----------------
__global__ void k_scan1v(int* __restrict__ data, int* __restrict__ bsum) {
    __shared__ int lds[256];
    int t = threadIdx.x, b = blockIdx.x;
    int base = b * 1024 + t * 4;
    int v0 = (base + 0 < LCNT) ? data[base + 0] : 0;
    int v1 = (base + 1 < LCNT) ? data[base + 1] : 0;
    int v2 = (base + 2 < LCNT) ? data[base + 2] : 0;
    int v3 = (base + 3 < LCNT) ? data[base + 3] : 0;
    lds[t] = v0 + v1 + v2 + v3;
    __syncthreads();
    for (int off = 1; off < 256; off <<= 1) {
        int x = (t >= off) ? lds[t - off] : 0;
        __syncthreads();
        lds[t] += x;
        __syncthreads();
    }
    int excl = (t > 0) ? lds[t - 1] : 0;
    if (t == 255) bsum[b] = lds[255];
    if (base + 0 < LCNT) data[base + 0] = excl;
    if (base + 1 < LCNT) data[base + 1] = excl + v0;
    if (base + 2 < LCNT) data[base + 2] = excl + v0 + v1;
    if (base + 3 < LCNT) data[base + 3] = excl + v0 + v1 + v2;
}

__global__ void k_scan2v(int* __restrict__ bsum) {
    __shared__ int lds[256];
    int t = threadIdx.x;
    int v = (t < SCB) ? bsum[t] : 0;
    lds[t] = v;
    __syncthreads();
    for (int off = 1; off < 256; off <<= 1) {
        int x = (t >= off) ? lds[t - off] : 0;
        __syncthreads();
        lds[t] += x;
        __syncthreads();
    }
    if (t < SCB) bsum[t] = lds[t] - v;  // exclusive
    if (t == SCB - 1) bsum[SCB] = lds[t];  // total valid edges
}

__global__ void k_scan3v(int* __restrict__ data, const int* __restrict__ bsum) {
    int i = blockIdx.x * 256 + threadIdx.x;
    if (i < LCNT) data[i] += bsum[i >> 10];
    else if (i == LCNT) data[LCNT] = bsum[SCB];
}

// ---------------- CSR build: pass 2, chunk -> LDS bucket-sort -> reserved slots ----------------
__global__ __launch_bounds__(256) void k_scatter2(const void* __restrict__ ei,
                                                  const int* __restrict__ flag,
                                                  const int* __restrict__ scanned,
                                                  unsigned* __restrict__ staging) {
    __shared__ int cnt[512], excl[512], cur[512], gbase[512];
    __shared__ unsigned lbuf[CH];
    __shared__ unsigned short lbkt[CH];
    const int t = threadIdx.x, blk = blockIdx.x;
    cnt[t] = 0; cnt[t + 256] = 0;
    __syncthreads();
    const int is64 = *flag;
    const int e0 = blk * CH;
    const int elim = min(NE, e0 + CH);
    unsigned recs[EPT];
    int bkts[EPT];
#pragma unroll
    for (int j = 0; j < EPT; j++) {
        int e = e0 + j * 256 + t;
        int bk = -1; unsigned rc = 0;
        if (e < elim) {
            int s = edge_at(ei, is64, e);
            int d = edge_at(ei, is64, (long long)NE + e);
            if ((unsigned)s < NN && (unsigned)d < NN) {
                bk = d >> 8;
                rc = (unsigned)s | ((unsigned)(d & 255) << 17);
                atomicAdd(&cnt[bk], 1);
            }
        }
        recs[j] = rc; bkts[j] = bk;
    }
    __syncthreads();
    excl[t] = cnt[t]; excl[t + 256] = cnt[t + 256];
    __syncthreads();
    for (int off = 1; off < 512; off <<= 1) {
        int a0 = (t >= off) ? excl[t - off] : 0;
        int a1 = (t + 256 >= off) ? excl[t + 256 - off] : 0;
        __syncthreads();
        excl[t] += a0; excl[t + 256] += a1;
        __syncthreads();
    }
    int i0 = excl[t] - cnt[t], i1 = excl[t + 256] - cnt[t + 256];
    excl[t] = i0; excl[t + 256] = i1;
    cur[t] = i0; cur[t + 256] = i1;
    for (int b = t; b < NBUK; b += 256) gbase[b] = scanned[(size_t)b * NCHK + blk];
    __syncthreads();
#pragma unroll
    for (int j = 0; j < EPT; j++) {
        if (bkts[j] >= 0) {
            int pos = atomicAdd(&cur[bkts[j]], 1);
            lbuf[pos] = recs[j];
            lbkt[pos] = (unsigned short)bkts[j];
        }
    }
    __syncthreads();
    const int tot = excl[NBUK];
    for (int i = t; i < tot; i += 256) {
        int b = lbkt[i];
        staging[(size_t)gbase[b] + (i - excl[b])] = lbuf[i];
    }
}

// ---------------- CSR build: pass 3, per-bucket deg/row_off/dinv + sorted csr ----------------
__global__ __launch_bounds__(256) void k_phaseB2(const unsigned* __restrict__ staging,
                                                 const int* __restrict__ scanned,
                                                 float* __restrict__ dinv,
                                                 int* __restrict__ row_off,
                                                 int* __restrict__ csr) {
    __shared__ int cnt[256], excl[256], cur[256];
    __shared__ int buf[8192];
    const int t = threadIdx.x, b = blockIdx.x;
    const int node0 = b << 8;
    const int nlocal = min(256, NN - node0);
    const int seg_beg = scanned[(size_t)b * NCHK];
    const size_t nxt = (size_t)(b + 1) * NCHK;
    const int seg_end = scanned[nxt > (size_t)LCNT ? (size_t)LCNT : nxt];
    const int len = min(seg_end - seg_beg, 8192);
    cnt[t] = 0;
    __syncthreads();
    for (int i = t; i < len; i += 256) {
        unsigned r = staging[seg_beg + i];
        atomicAdd(&cnt[r >> 17], 1);
    }
    __syncthreads();
    excl[t] = cnt[t];
    __syncthreads();
    for (int off = 1; off < 256; off <<= 1) {
        int x = (t >= off) ? excl[t - off] : 0;
        __syncthreads();
        excl[t] += x;
        __syncthreads();
    }
    int ex = excl[t] - cnt[t];
    excl[t] = ex;
    cur[t] = ex;
    if (t < nlocal) {
        row_off[node0 + t] = seg_beg + ex;
        dinv[node0 + t] = rsqrtf((float)(cnt[t] + 1));  // +1 self loop
    }
    if (b == NBUK - 1 && t == 0) row_off[NN] = seg_end;
    __syncthreads();
    for (int i = t; i < len; i += 256) {
        unsigned r = staging[seg_beg + i];
        int pos = atomicAdd(&cur[r >> 17], 1);
        buf[pos] = (int)(r & 0x1FFFFu);
    }
    __syncthreads();
    for (int i = t; i < len; i += 256) csr[seg_beg + i] = buf[i];
}

// ---------------- GEMM: H[n,:] = dinv[n] * (X[n,:] @ W) ----------------
// One 32-row tile per block (grid = 3125) for perfect load balance.
template <int C, int MINW>
__global__ __launch_bounds__(256, MINW) void k_gemm(const float* __restrict__ X,
                                                    const float* __restrict__ W,
                                                    const float* __restrict__ dinv,
                                                    float* __restrict__ H) {
    constexpr int K = 128, R = 32;
    constexpr int COLG = C / 4;          // col groups (float4)
    constexpr int TR = R / (256 / COLG); // rows per thread: 4 (C=128), 2 (C=64)
    __shared__ float ws[K * C];
    __shared__ float xs[R * K];
    const int tid = threadIdx.x;
    const int row0 = blockIdx.x * R;
    for (int i = tid; i < K * C / 4; i += 256)
        ((float4*)ws)[i] = ((const float4*)W)[i];
    for (int i = tid; i < R * K / 4; i += 256)
        ((float4*)xs)[i] = ((const float4*)(X + (size_t)row0 * K))[i];
    const int cg = tid % COLG;
    const int rs = tid / COLG;
    __syncthreads();
    float4 acc[TR];
#pragma unroll
    for (int r = 0; r < TR; r++) acc[r] = make_float4(0.f, 0.f, 0.f, 0.f);
#pragma unroll 4
    for (int k0 = 0; k0 < K; k0 += 4) {
        float4 xv[TR];
#pragma unroll
        for (int r = 0; r < TR; r++)
            xv[r] = *(const float4*)&xs[(rs * TR + r) * K + k0];
#pragma unroll
        for (int kk = 0; kk < 4; kk++) {
            float4 w = *(const float4*)&ws[(k0 + kk) * C + cg * 4];
#pragma unroll
            for (int r = 0; r < TR; r++) {
                float xr = (kk == 0) ? xv[r].x : (kk == 1) ? xv[r].y
                         : (kk == 2) ? xv[r].z : xv[r].w;
                acc[r].x = fmaf(xr, w.x, acc[r].x);
                acc[r].y = fmaf(xr, w.y, acc[r].y);
                acc[r].z = fmaf(xr, w.z, acc[r].z);
                acc[r].w = fmaf(xr, w.w, acc[r].w);
            }
        }
    }
#pragma unroll
    for (int r = 0; r < TR; r++) {
        int row = row0 + rs * TR + r;
        float dv = dinv[row];
        float4 o;
        o.x = acc[r].x * dv; o.y = acc[r].y * dv;
        o.z = acc[r].z * dv; o.w = acc[r].w * dv;
        *(float4*)&H[(size_t)row * C + cg * 4] = o;
    }
}

// ---------------- Aggregation C=128: 2 nodes/wave, float4 lanes, 8 gathers in flight ----
template <bool RELU>
__global__ __launch_bounds__(256) void k_agg128(const float* __restrict__ H,
                                                const int* __restrict__ row_off,
                                                const int* __restrict__ csr,
                                                const float* __restrict__ dinv,
                                                const float* __restrict__ bias,
                                                float* __restrict__ OUT) {
    const int tid = threadIdx.x;
    const int wid = tid >> 6, lane = tid & 63;
    const int half = lane >> 5, il = lane & 31;
    const int node = blockIdx.x * 8 + wid * 2 + half;  // NN = 12500*8 exactly
    const int beg = row_off[node];
    const int cnt = row_off[node + 1] - beg;
    const int tmax = max(cnt, __shfl(cnt, lane ^ 32));
    const float4* __restrict__ H4 = (const float4*)H;
    float4 acc = make_float4(0.f, 0.f, 0.f, 0.f);
    for (int j0 = 0; j0 < tmax; j0 += 32) {
        int sidx = node;
        if (j0 + il < cnt) sidx = csr[beg + j0 + il];
        const int rem = min(32, tmax - j0);
        for (int u = 0; u < rem; u += 4) {
            float4 v[4]; float m[4];
#pragma unroll
            for (int k = 0; k < 4; k++) {
                int s = __shfl(sidx, half * 32 + u + k);
                v[k] = H4[(size_t)s * 32 + il];
                m[k] = (j0 + u + k < cnt) ? 1.f : 0.f;
            }
#pragma unroll
            for (int k = 0; k < 4; k++) {
                acc.x = fmaf(m[k], v[k].x, acc.x);
                acc.y = fmaf(m[k], v[k].y, acc.y);
                acc.z = fmaf(m[k], v[k].z, acc.z);
                acc.w = fmaf(m[k], v[k].w, acc.w);
            }
        }
    }
    float4 hv = H4[(size_t)node * 32 + il];
    acc.x += hv.x; acc.y += hv.y; acc.z += hv.z; acc.w += hv.w;
    const float dv = dinv[node];
    float4 bb = ((const float4*)bias)[il];
    float4 o;
    o.x = fmaf(acc.x, dv, bb.x); o.y = fmaf(acc.y, dv, bb.y);
    o.z = fmaf(acc.z, dv, bb.z); o.w = fmaf(acc.w, dv, bb.w);
    if (RELU) {
        o.x = fmaxf(o.x, 0.f); o.y = fmaxf(o.y, 0.f);
        o.z = fmaxf(o.z, 0.f); o.w = fmaxf(o.w, 0.f);
    }
    ((float4*)OUT)[(size_t)node * 32 + il] = o;
}

// ---------------- Aggregation C=64: 4 nodes/wave, float4 lanes ----------------
__global__ __launch_bounds__(256) void k_agg64(const float* __restrict__ H,
                                               const int* __restrict__ row_off,
                                               const int* __restrict__ csr,
                                               const float* __restrict__ dinv,
                                               const float* __restrict__ bias,
                                               float* __restrict__ OUT) {
    const int tid = threadIdx.x;
    const int wid = tid >> 6, lane = tid & 63;
    const int q = lane >> 4, il = lane & 15;
    const int node = blockIdx.x * 16 + wid * 4 + q;  // NN = 6250*16 exactly
    const int beg = row_off[node];
    const int cnt = row_off[node + 1] - beg;
    int m1 = max(cnt, __shfl(cnt, lane ^ 16));
    const int tmax = max(m1, __shfl(m1, lane ^ 32));
    const float4* __restrict__ H4 = (const float4*)H;
    float4 acc = make_float4(0.f, 0.f, 0.f, 0.f);
    for (int j0 = 0; j0 < tmax; j0 += 16) {
        int sidx = node;
        if (j0 + il < cnt) sidx = csr[beg + j0 + il];
        const int rem = min(16, tmax - j0);
        for (int u = 0; u < rem; u += 4) {
            float4 v[4]; float m[4];
#pragma unroll
            for (int k = 0; k < 4; k++) {
                int s = __shfl(sidx, q * 16 + u + k);
                v[k] = H4[(size_t)s * 16 + il];
                m[k] = (j0 + u + k < cnt) ? 1.f : 0.f;
            }
#pragma unroll
            for (int k = 0; k < 4; k++) {
                acc.x = fmaf(m[k], v[k].x, acc.x);
                acc.y = fmaf(m[k], v[k].y, acc.y);
                acc.z = fmaf(m[k], v[k].z, acc.z);
                acc.w = fmaf(m[k], v[k].w, acc.w);
            }
        }
    }
    float4 hv = H4[(size_t)node * 16 + il];
    acc.x += hv.x; acc.y += hv.y; acc.z += hv.z; acc.w += hv.w;
    const float dv = dinv[node];
    float4 bb = ((const float4*)bias)[il];
    float4 o;
    o.x = fmaf(acc.x, dv, bb.x); o.y = fmaf(acc.y, dv, bb.y);
    o.z = fmaf(acc.z, dv, bb.z); o.w = fmaf(acc.w, dv, bb.w);
    ((float4*)OUT)[(size_t)node * 16 + il] = o;
}

extern "C" void kernel_launch(void* const* d_in, const int* in_sizes, int n_in,
                              void* d_out, int out_size, void* d_ws, size_t ws_size,
                              hipStream_t stream) {
    const float* x  = (const float*)d_in[0];
    const void*  ei = d_in[1];
    const float* W1 = (const float*)d_in[2];
    const float* b1 = (const float*)d_in[3];
    const float* W2 = (const float*)d_in[4];
    const float* b2 = (const float*)d_in[5];
    const float* W3 = (const float*)d_in[6];
    const float* b3 = (const float*)d_in[7];
    float* out = (float*)d_out;

    char* wsp = (char*)d_ws;
    size_t off = 0;
    auto alloc = [&](size_t bytes) -> void* {
        void* p = wsp + off;
        off += (bytes + 255) & ~(size_t)255;
        return p;
    };
    float* A       = (float*)alloc((size_t)NN * 128 * 4);
    float* B       = (float*)alloc((size_t)NN * 128 * 4);
    float* dinv    = (float*)alloc((size_t)NN * 4);
    int*   row_off = (int*)alloc(((size_t)NN + 1) * 4);
    int*   counts  = (int*)alloc(((size_t)LCNT + 1) * 4);
    int*   bsum    = (int*)alloc(((size_t)SCB + 1) * 4);
    int*   csr     = (int*)alloc((size_t)NE * 4);
    int*   flag    = (int*)alloc(256);
    if (off > ws_size) return;

    unsigned* staging = (unsigned*)B;  // aliases B (dead until agg layer 1)

    k_detect_i64<<<1, 256, 0, stream>>>((const unsigned*)ei, flag);
    k_count<<<NCHK, 256, 0, stream>>>(ei, flag, counts);
    k_scan1v<<<SCB, 256, 0, stream>>>(counts, bsum);
    k_scan2v<<<1, 256, 0, stream>>>(bsum);
    k_scan3v<<<(LCNT + 1 + 255) / 256, 256, 0, stream>>>(counts, bsum);
    k_scatter2<<<NCHK, 256, 0, stream>>>(ei, flag, counts, staging);
    k_phaseB2<<<NBUK, 256, 0, stream>>>(staging, counts, dinv, row_off, csr);

    constexpr int NTILES = NN / 32;  // 3125
    k_gemm<128, 2><<<NTILES, 256, 0, stream>>>(x, W1, dinv, A);
    k_agg128<true><<<NN / 8, 256, 0, stream>>>(A, row_off, csr, dinv, b1, B);
    k_gemm<128, 2><<<NTILES, 256, 0, stream>>>(B, W2, dinv, A);
    k_agg128<true><<<NN / 8, 256, 0, stream>>>(A, row_off, csr, dinv, b2, B);
    k_gemm<64, 3><<<NTILES, 256, 0, stream>>>(B, W3, dinv, A);
    k_agg64<<<NN / 16, 256, 0, stream>>>(A, row_off, csr, dinv, b3, out);
}

// Round 5
// 359.108 us; speedup vs baseline: 1.4210x; 1.4210x over previous
//
#include <hip/hip_runtime.h>
#include <hip/hip_bf16.h>
#include <hip/hip_fp16.h>

#define NN 100000
#define NE 1600000
constexpr int NBUK = (NN + 255) / 256;      // 391 dst buckets of 256 nodes
constexpr int CH   = 4096;                  // edges per chunk
constexpr int EPT  = CH / 256;              // 16 edges per thread
constexpr int NCHK = (NE + CH - 1) / CH;    // 391 chunks
constexpr int LCNT = NBUK * NCHK;           // 152,881 counters
constexpr int SCB  = (LCNT + 1023) / 1024;  // 150 scan blocks

__device__ __forceinline__ float h2f(unsigned short h) {
    return __half2float(__ushort_as_half(h));
}
__device__ __forceinline__ unsigned short f2h(float f) {
    return __half_as_ushort(__float2half(f));  // RN
}

// ---------------- edge dtype detection ----------------
__global__ void k_detect_i64(const unsigned* __restrict__ ei, int* __restrict__ flag) {
    __shared__ int any_nz;
    if (threadIdx.x == 0) any_nz = 0;
    __syncthreads();
    int nz = 0;
    for (int i = threadIdx.x; i < 2048; i += 256)
        if (ei[2 * i + 1] != 0u) nz = 1;
    if (nz) atomicExch(&any_nz, 1);
    __syncthreads();
    if (threadIdx.x == 0) *flag = (any_nz == 0) ? 1 : 0;
}

__device__ __forceinline__ int edge_at(const void* ei, int is64, long long idx) {
    if (is64) return (int)((const long long*)ei)[idx];
    return ((const int*)ei)[idx];
}

// ---------------- CSR build: pass 1, per-chunk LDS bucket histogram ----------------
__global__ __launch_bounds__(256) void k_count(const void* __restrict__ ei,
                                               const int* __restrict__ flag,
                                               int* __restrict__ counts) {
    __shared__ int cnt[NBUK];
    const int t = threadIdx.x, blk = blockIdx.x;
    for (int i = t; i < NBUK; i += 256) cnt[i] = 0;
    __syncthreads();
    const int is64 = *flag;
    const int e0 = blk * CH;
    const int elim = min(NE, e0 + CH);
#pragma unroll
    for (int j = 0; j < EPT; j++) {
        int e = e0 + j * 256 + t;
        if (e < elim) {
            int s = edge_at(ei, is64, e);
            int d = edge_at(ei, is64, (long long)NE + e);
            if ((unsigned)s < NN && (unsigned)d < NN) atomicAdd(&cnt[d >> 8], 1);
        }
    }
    __syncthreads();
    for (int i = t; i < NBUK; i += 256) counts[(size_t)i * NCHK + blk] = cnt[i];
}

// ---------------- exclusive scan of counts[LCNT] (in place) ----------------
__global__ void k_scan1v(int* __restrict__ data, int* __restrict__ bsum) {
    __shared__ int lds[256];
    int t = threadIdx.x, b = blockIdx.x;
    int base = b * 1024 + t * 4;
    int v0 = (base + 0 < LCNT) ? data[base + 0] : 0;
    int v1 = (base + 1 < LCNT) ? data[base + 1] : 0;
    int v2 = (base + 2 < LCNT) ? data[base + 2] : 0;
    int v3 = (base + 3 < LCNT) ? data[base + 3] : 0;
    lds[t] = v0 + v1 + v2 + v3;
    __syncthreads();
    for (int off = 1; off < 256; off <<= 1) {
        int x = (t >= off) ? lds[t - off] : 0;
        __syncthreads();
        lds[t] += x;
        __syncthreads();
    }
    int excl = (t > 0) ? lds[t - 1] : 0;
    if (t == 255) bsum[b] = lds[255];
    if (base + 0 < LCNT) data[base + 0] = excl;
    if (base + 1 < LCNT) data[base + 1] = excl + v0;
    if (base + 2 < LCNT) data[base + 2] = excl + v0 + v1;
    if (base + 3 < LCNT) data[base + 3] = excl + v0 + v1 + v2;
}

__global__ void k_scan2v(int* __restrict__ bsum) {
    __shared__ int lds[256];
    int t = threadIdx.x;
    int v = (t < SCB) ? bsum[t] : 0;
    lds[t] = v;
    __syncthreads();
    for (int off = 1; off < 256; off <<= 1) {
        int x = (t >= off) ? lds[t - off] : 0;
        __syncthreads();
        lds[t] += x;
        __syncthreads();
    }
    if (t < SCB) bsum[t] = lds[t] - v;  // exclusive
    if (t == SCB - 1) bsum[SCB] = lds[t];  // total valid edges
}

__global__ void k_scan3v(int* __restrict__ data, const int* __restrict__ bsum) {
    int i = blockIdx.x * 256 + threadIdx.x;
    if (i < LCNT) data[i] += bsum[i >> 10];
    else if (i == LCNT) data[LCNT] = bsum[SCB];
}

// ---------------- CSR build: pass 2, chunk -> LDS bucket-sort -> reserved slots ----------------
__global__ __launch_bounds__(256) void k_scatter2(const void* __restrict__ ei,
                                                  const int* __restrict__ flag,
                                                  const int* __restrict__ scanned,
                                                  unsigned* __restrict__ staging) {
    __shared__ int cnt[512], excl[512], cur[512], gbase[512];
    __shared__ unsigned lbuf[CH];
    __shared__ unsigned short lbkt[CH];
    const int t = threadIdx.x, blk = blockIdx.x;
    cnt[t] = 0; cnt[t + 256] = 0;
    __syncthreads();
    const int is64 = *flag;
    const int e0 = blk * CH;
    const int elim = min(NE, e0 + CH);
    unsigned recs[EPT];
    int bkts[EPT];
#pragma unroll
    for (int j = 0; j < EPT; j++) {
        int e = e0 + j * 256 + t;
        int bk = -1; unsigned rc = 0;
        if (e < elim) {
            int s = edge_at(ei, is64, e);
            int d = edge_at(ei, is64, (long long)NE + e);
            if ((unsigned)s < NN && (unsigned)d < NN) {
                bk = d >> 8;
                rc = (unsigned)s | ((unsigned)(d & 255) << 17);
                atomicAdd(&cnt[bk], 1);
            }
        }
        recs[j] = rc; bkts[j] = bk;
    }
    __syncthreads();
    excl[t] = cnt[t]; excl[t + 256] = cnt[t + 256];
    __syncthreads();
    for (int off = 1; off < 512; off <<= 1) {
        int a0 = (t >= off) ? excl[t - off] : 0;
        int a1 = (t + 256 >= off) ? excl[t + 256 - off] : 0;
        __syncthreads();
        excl[t] += a0; excl[t + 256] += a1;
        __syncthreads();
    }
    int i0 = excl[t] - cnt[t], i1 = excl[t + 256] - cnt[t + 256];
    excl[t] = i0; excl[t + 256] = i1;
    cur[t] = i0; cur[t + 256] = i1;
    for (int b = t; b < NBUK; b += 256) gbase[b] = scanned[(size_t)b * NCHK + blk];
    __syncthreads();
#pragma unroll
    for (int j = 0; j < EPT; j++) {
        if (bkts[j] >= 0) {
            int pos = atomicAdd(&cur[bkts[j]], 1);
            lbuf[pos] = recs[j];
            lbkt[pos] = (unsigned short)bkts[j];
        }
    }
    __syncthreads();
    const int tot = excl[NBUK];
    for (int i = t; i < tot; i += 256) {
        int b = lbkt[i];
        staging[(size_t)gbase[b] + (i - excl[b])] = lbuf[i];
    }
}

// ---------------- CSR build: pass 3, per-bucket deg/row_off/dinv + sorted csr ----------------
__global__ __launch_bounds__(256) void k_phaseB2(const unsigned* __restrict__ staging,
                                                 const int* __restrict__ scanned,
                                                 float* __restrict__ dinv,
                                                 int* __restrict__ row_off,
                                                 int* __restrict__ csr) {
    __shared__ int cnt[256], excl[256], cur[256];
    __shared__ int buf[8192];
    const int t = threadIdx.x, b = blockIdx.x;
    const int node0 = b << 8;
    const int nlocal = min(256, NN - node0);
    const int seg_beg = scanned[(size_t)b * NCHK];
    const size_t nxt = (size_t)(b + 1) * NCHK;
    const int seg_end = scanned[nxt > (size_t)LCNT ? (size_t)LCNT : nxt];
    const int len = min(seg_end - seg_beg, 8192);
    cnt[t] = 0;
    __syncthreads();
    for (int i = t; i < len; i += 256) {
        unsigned r = staging[seg_beg + i];
        atomicAdd(&cnt[r >> 17], 1);
    }
    __syncthreads();
    excl[t] = cnt[t];
    __syncthreads();
    for (int off = 1; off < 256; off <<= 1) {
        int x = (t >= off) ? excl[t - off] : 0;
        __syncthreads();
        excl[t] += x;
        __syncthreads();
    }
    int ex = excl[t] - cnt[t];
    excl[t] = ex;
    cur[t] = ex;
    if (t < nlocal) {
        row_off[node0 + t] = seg_beg + ex;
        dinv[node0 + t] = rsqrtf((float)(cnt[t] + 1));  // +1 self loop
    }
    if (b == NBUK - 1 && t == 0) row_off[NN] = seg_end;
    __syncthreads();
    for (int i = t; i < len; i += 256) {
        unsigned r = staging[seg_beg + i];
        int pos = atomicAdd(&cur[r >> 17], 1);
        buf[pos] = (int)(r & 0x1FFFFu);
    }
    __syncthreads();
    for (int i = t; i < len; i += 256) csr[seg_beg + i] = buf[i];
}

// ---------------- GEMM: Hf16[n,:] = f16(dinv[n] * (X[n,:] @ W)) ----------------
// One 32-row tile per block (grid = 3125) for perfect load balance.
template <int C, int MINW>
__global__ __launch_bounds__(256, MINW) void k_gemm(const float* __restrict__ X,
                                                    const float* __restrict__ W,
                                                    const float* __restrict__ dinv,
                                                    unsigned short* __restrict__ H) {
    constexpr int K = 128, R = 32;
    constexpr int COLG = C / 4;          // col groups (float4)
    constexpr int TR = R / (256 / COLG); // rows per thread: 4 (C=128), 2 (C=64)
    __shared__ float ws[K * C];
    __shared__ float xs[R * K];
    const int tid = threadIdx.x;
    const int row0 = blockIdx.x * R;
    for (int i = tid; i < K * C / 4; i += 256)
        ((float4*)ws)[i] = ((const float4*)W)[i];
    for (int i = tid; i < R * K / 4; i += 256)
        ((float4*)xs)[i] = ((const float4*)(X + (size_t)row0 * K))[i];
    const int cg = tid % COLG;
    const int rs = tid / COLG;
    __syncthreads();
    float4 acc[TR];
#pragma unroll
    for (int r = 0; r < TR; r++) acc[r] = make_float4(0.f, 0.f, 0.f, 0.f);
#pragma unroll 4
    for (int k0 = 0; k0 < K; k0 += 4) {
        float4 xv[TR];
#pragma unroll
        for (int r = 0; r < TR; r++)
            xv[r] = *(const float4*)&xs[(rs * TR + r) * K + k0];
#pragma unroll
        for (int kk = 0; kk < 4; kk++) {
            float4 w = *(const float4*)&ws[(k0 + kk) * C + cg * 4];
#pragma unroll
            for (int r = 0; r < TR; r++) {
                float xr = (kk == 0) ? xv[r].x : (kk == 1) ? xv[r].y
                         : (kk == 2) ? xv[r].z : xv[r].w;
                acc[r].x = fmaf(xr, w.x, acc[r].x);
                acc[r].y = fmaf(xr, w.y, acc[r].y);
                acc[r].z = fmaf(xr, w.z, acc[r].z);
                acc[r].w = fmaf(xr, w.w, acc[r].w);
            }
        }
    }
#pragma unroll
    for (int r = 0; r < TR; r++) {
        int row = row0 + rs * TR + r;
        float dv = dinv[row];
        ushort4 o;
        o.x = f2h(acc[r].x * dv); o.y = f2h(acc[r].y * dv);
        o.z = f2h(acc[r].z * dv); o.w = f2h(acc[r].w * dv);
        *(ushort4*)&H[(size_t)row * C + cg * 4] = o;
    }
}

// ---------------- Aggregation C=128 (f16 H): 2 nodes/wave, 8 gathers in flight ----
template <bool RELU>
__global__ __launch_bounds__(256) void k_agg128(const unsigned short* __restrict__ H,
                                                const int* __restrict__ row_off,
                                                const int* __restrict__ csr,
                                                const float* __restrict__ dinv,
                                                const float* __restrict__ bias,
                                                float* __restrict__ OUT) {
    const int tid = threadIdx.x;
    const int wid = tid >> 6, lane = tid & 63;
    const int half = lane >> 5, il = lane & 31;
    const int node = blockIdx.x * 8 + wid * 2 + half;  // NN = 12500*8 exactly
    const int beg = row_off[node];
    const int cnt = row_off[node + 1] - beg;
    const int tmax = max(cnt, __shfl(cnt, lane ^ 32));
    const ushort4* __restrict__ Hh = (const ushort4*)H;  // 32 ushort4 per row
    float4 acc = make_float4(0.f, 0.f, 0.f, 0.f);
    for (int j0 = 0; j0 < tmax; j0 += 32) {
        int sidx = node;
        if (j0 + il < cnt) sidx = csr[beg + j0 + il];
        const int rem = min(32, tmax - j0);
        for (int u = 0; u < rem; u += 8) {
            ushort4 v[8]; float m[8];
#pragma unroll
            for (int k = 0; k < 8; k++) {
                int s = __shfl(sidx, half * 32 + u + k);
                v[k] = Hh[(size_t)s * 32 + il];
                m[k] = (j0 + u + k < cnt) ? 1.f : 0.f;
            }
#pragma unroll
            for (int k = 0; k < 8; k++) {
                acc.x = fmaf(m[k], h2f(v[k].x), acc.x);
                acc.y = fmaf(m[k], h2f(v[k].y), acc.y);
                acc.z = fmaf(m[k], h2f(v[k].z), acc.z);
                acc.w = fmaf(m[k], h2f(v[k].w), acc.w);
            }
        }
    }
    ushort4 hv = Hh[(size_t)node * 32 + il];
    acc.x += h2f(hv.x); acc.y += h2f(hv.y);
    acc.z += h2f(hv.z); acc.w += h2f(hv.w);
    const float dv = dinv[node];
    float4 bb = ((const float4*)bias)[il];
    float4 o;
    o.x = fmaf(acc.x, dv, bb.x); o.y = fmaf(acc.y, dv, bb.y);
    o.z = fmaf(acc.z, dv, bb.z); o.w = fmaf(acc.w, dv, bb.w);
    if (RELU) {
        o.x = fmaxf(o.x, 0.f); o.y = fmaxf(o.y, 0.f);
        o.z = fmaxf(o.z, 0.f); o.w = fmaxf(o.w, 0.f);
    }
    ((float4*)OUT)[(size_t)node * 32 + il] = o;
}

// ---------------- Aggregation C=64 (f16 H): 4 nodes/wave ----------------
__global__ __launch_bounds__(256) void k_agg64(const unsigned short* __restrict__ H,
                                               const int* __restrict__ row_off,
                                               const int* __restrict__ csr,
                                               const float* __restrict__ dinv,
                                               const float* __restrict__ bias,
                                               float* __restrict__ OUT) {
    const int tid = threadIdx.x;
    const int wid = tid >> 6, lane = tid & 63;
    const int q = lane >> 4, il = lane & 15;
    const int node = blockIdx.x * 16 + wid * 4 + q;  // NN = 6250*16 exactly
    const int beg = row_off[node];
    const int cnt = row_off[node + 1] - beg;
    int m1 = max(cnt, __shfl(cnt, lane ^ 16));
    const int tmax = max(m1, __shfl(m1, lane ^ 32));
    const ushort4* __restrict__ Hh = (const ushort4*)H;  // 16 ushort4 per row
    float4 acc = make_float4(0.f, 0.f, 0.f, 0.f);
    for (int j0 = 0; j0 < tmax; j0 += 16) {
        int sidx = node;
        if (j0 + il < cnt) sidx = csr[beg + j0 + il];
        const int rem = min(16, tmax - j0);
        for (int u = 0; u < rem; u += 8) {
            ushort4 v[8]; float m[8];
#pragma unroll
            for (int k = 0; k < 8; k++) {
                int s = __shfl(sidx, q * 16 + u + k);
                v[k] = Hh[(size_t)s * 16 + il];
                m[k] = (j0 + u + k < cnt) ? 1.f : 0.f;
            }
#pragma unroll
            for (int k = 0; k < 8; k++) {
                acc.x = fmaf(m[k], h2f(v[k].x), acc.x);
                acc.y = fmaf(m[k], h2f(v[k].y), acc.y);
                acc.z = fmaf(m[k], h2f(v[k].z), acc.z);
                acc.w = fmaf(m[k], h2f(v[k].w), acc.w);
            }
        }
    }
    ushort4 hv = Hh[(size_t)node * 16 + il];
    acc.x += h2f(hv.x); acc.y += h2f(hv.y);
    acc.z += h2f(hv.z); acc.w += h2f(hv.w);
    const float dv = dinv[node];
    float4 bb = ((const float4*)bias)[il];
    float4 o;
    o.x = fmaf(acc.x, dv, bb.x); o.y = fmaf(acc.y, dv, bb.y);
    o.z = fmaf(acc.z, dv, bb.z); o.w = fmaf(acc.w, dv, bb.w);
    ((float4*)OUT)[(size_t)node * 16 + il] = o;
}

extern "C" void kernel_launch(void* const* d_in, const int* in_sizes, int n_in,
                              void* d_out, int out_size, void* d_ws, size_t ws_size,
                              hipStream_t stream) {
    const float* x  = (const float*)d_in[0];
    const void*  ei = d_in[1];
    const float* W1 = (const float*)d_in[2];
    const float* b1 = (const float*)d_in[3];
    const float* W2 = (const float*)d_in[4];
    const float* b2 = (const float*)d_in[5];
    const float* W3 = (const float*)d_in[6];
    const float* b3 = (const float*)d_in[7];
    float* out = (float*)d_out;

    char* wsp = (char*)d_ws;
    size_t off = 0;
    auto alloc = [&](size_t bytes) -> void* {
        void* p = wsp + off;
        off += (bytes + 255) & ~(size_t)255;
        return p;
    };
    unsigned short* A = (unsigned short*)alloc((size_t)NN * 128 * 2);  // f16 H
    float* B       = (float*)alloc((size_t)NN * 128 * 4);              // f32 agg out
    float* dinv    = (float*)alloc((size_t)NN * 4);
    int*   row_off = (int*)alloc(((size_t)NN + 1) * 4);
    int*   counts  = (int*)alloc(((size_t)LCNT + 1) * 4);
    int*   bsum    = (int*)alloc(((size_t)SCB + 1) * 4);
    int*   csr     = (int*)alloc((size_t)NE * 4);
    int*   flag    = (int*)alloc(256);
    if (off > ws_size) return;

    unsigned* staging = (unsigned*)B;  // aliases B (dead until agg layer 1)

    k_detect_i64<<<1, 256, 0, stream>>>((const unsigned*)ei, flag);
    k_count<<<NCHK, 256, 0, stream>>>(ei, flag, counts);
    k_scan1v<<<SCB, 256, 0, stream>>>(counts, bsum);
    k_scan2v<<<1, 256, 0, stream>>>(bsum);
    k_scan3v<<<(LCNT + 1 + 255) / 256, 256, 0, stream>>>(counts, bsum);
    k_scatter2<<<NCHK, 256, 0, stream>>>(ei, flag, counts, staging);
    k_phaseB2<<<NBUK, 256, 0, stream>>>(staging, counts, dinv, row_off, csr);

    constexpr int NTILES = NN / 32;  // 3125
    k_gemm<128, 2><<<NTILES, 256, 0, stream>>>(x, W1, dinv, A);
    k_agg128<true><<<NN / 8, 256, 0, stream>>>(A, row_off, csr, dinv, b1, B);
    k_gemm<128, 2><<<NTILES, 256, 0, stream>>>(B, W2, dinv, A);
    k_agg128<true><<<NN / 8, 256, 0, stream>>>(A, row_off, csr, dinv, b2, B);
    k_gemm<64, 3><<<NTILES, 256, 0, stream>>>(B, W3, dinv, A);
    k_agg64<<<NN / 16, 256, 0, stream>>>(A, row_off, csr, dinv, b3, out);
}

// Round 6
// 246.026 us; speedup vs baseline: 2.0742x; 1.4596x over previous
//
#include <hip/hip_runtime.h>
#include <hip/hip_bf16.h>
#include <hip/hip_fp16.h>

#define NN 100000
#define NE 1600000
constexpr int NN_PAD = 100032;              // 64-row padded (1563 blocks)
constexpr int NBUK = (NN + 255) / 256;      // 391 dst buckets of 256 nodes
constexpr int CH   = 4096;                  // edges per chunk
constexpr int EPT  = CH / 256;              // 16 edges per thread
constexpr int NCHK = (NE + CH - 1) / CH;    // 391 chunks
constexpr int LCNT = NBUK * NCHK;           // 152,881 counters
constexpr int SCB  = (LCNT + 1023) / 1024;  // 150 scan blocks

typedef _Float16 f16x8 __attribute__((ext_vector_type(8)));
typedef float f32x4 __attribute__((ext_vector_type(4)));

__device__ __forceinline__ float h2f(unsigned short h) {
    return __half2float(__ushort_as_half(h));
}
__device__ __forceinline__ unsigned short f2h(float f) {
    return __half_as_ushort(__float2half(f));  // RN
}

// ---------------- edge dtype detection ----------------
__global__ void k_detect_i64(const unsigned* __restrict__ ei, int* __restrict__ flag) {
    __shared__ int any_nz;
    if (threadIdx.x == 0) any_nz = 0;
    __syncthreads();
    int nz = 0;
    for (int i = threadIdx.x; i < 2048; i += 256)
        if (ei[2 * i + 1] != 0u) nz = 1;
    if (nz) atomicExch(&any_nz, 1);
    __syncthreads();
    if (threadIdx.x == 0) *flag = (any_nz == 0) ? 1 : 0;
}

__device__ __forceinline__ int edge_at(const void* ei, int is64, long long idx) {
    if (is64) return (int)((const long long*)ei)[idx];
    return ((const int*)ei)[idx];
}

// ---------------- CSR build: pass 1, per-chunk LDS bucket histogram ----------------
__global__ __launch_bounds__(256) void k_count(const void* __restrict__ ei,
                                               const int* __restrict__ flag,
                                               int* __restrict__ counts) {
    __shared__ int cnt[NBUK];
    const int t = threadIdx.x, blk = blockIdx.x;
    for (int i = t; i < NBUK; i += 256) cnt[i] = 0;
    __syncthreads();
    const int is64 = *flag;
    const int e0 = blk * CH;
    const int elim = min(NE, e0 + CH);
#pragma unroll
    for (int j = 0; j < EPT; j++) {
        int e = e0 + j * 256 + t;
        if (e < elim) {
            int s = edge_at(ei, is64, e);
            int d = edge_at(ei, is64, (long long)NE + e);
            if ((unsigned)s < NN && (unsigned)d < NN) atomicAdd(&cnt[d >> 8], 1);
        }
    }
    __syncthreads();
    for (int i = t; i < NBUK; i += 256) counts[(size_t)i * NCHK + blk] = cnt[i];
}

// ---------------- exclusive scan of counts[LCNT] (in place) ----------------
__global__ void k_scan1v(int* __restrict__ data, int* __restrict__ bsum) {
    __shared__ int lds[256];
    int t = threadIdx.x, b = blockIdx.x;
    int base = b * 1024 + t * 4;
    int v0 = (base + 0 < LCNT) ? data[base + 0] : 0;
    int v1 = (base + 1 < LCNT) ? data[base + 1] : 0;
    int v2 = (base + 2 < LCNT) ? data[base + 2] : 0;
    int v3 = (base + 3 < LCNT) ? data[base + 3] : 0;
    lds[t] = v0 + v1 + v2 + v3;
    __syncthreads();
    for (int off = 1; off < 256; off <<= 1) {
        int x = (t >= off) ? lds[t - off] : 0;
        __syncthreads();
        lds[t] += x;
        __syncthreads();
    }
    int excl = (t > 0) ? lds[t - 1] : 0;
    if (t == 255) bsum[b] = lds[255];
    if (base + 0 < LCNT) data[base + 0] = excl;
    if (base + 1 < LCNT) data[base + 1] = excl + v0;
    if (base + 2 < LCNT) data[base + 2] = excl + v0 + v1;
    if (base + 3 < LCNT) data[base + 3] = excl + v0 + v1 + v2;
}

__global__ void k_scan2v(int* __restrict__ bsum) {
    __shared__ int lds[256];
    int t = threadIdx.x;
    int v = (t < SCB) ? bsum[t] : 0;
    lds[t] = v;
    __syncthreads();
    for (int off = 1; off < 256; off <<= 1) {
        int x = (t >= off) ? lds[t - off] : 0;
        __syncthreads();
        lds[t] += x;
        __syncthreads();
    }
    if (t < SCB) bsum[t] = lds[t] - v;  // exclusive
    if (t == SCB - 1) bsum[SCB] = lds[t];  // total valid edges
}

__global__ void k_scan3v(int* __restrict__ data, const int* __restrict__ bsum) {
    int i = blockIdx.x * 256 + threadIdx.x;
    if (i < LCNT) data[i] += bsum[i >> 10];
    else if (i == LCNT) data[LCNT] = bsum[SCB];
}

// ---------------- CSR build: pass 2, chunk -> LDS bucket-sort -> reserved slots ----------------
__global__ __launch_bounds__(256) void k_scatter2(const void* __restrict__ ei,
                                                  const int* __restrict__ flag,
                                                  const int* __restrict__ scanned,
                                                  unsigned* __restrict__ staging) {
    __shared__ int cnt[512], excl[512], cur[512], gbase[512];
    __shared__ unsigned lbuf[CH];
    __shared__ unsigned short lbkt[CH];
    const int t = threadIdx.x, blk = blockIdx.x;
    cnt[t] = 0; cnt[t + 256] = 0;
    __syncthreads();
    const int is64 = *flag;
    const int e0 = blk * CH;
    const int elim = min(NE, e0 + CH);
    unsigned recs[EPT];
    int bkts[EPT];
#pragma unroll
    for (int j = 0; j < EPT; j++) {
        int e = e0 + j * 256 + t;
        int bk = -1; unsigned rc = 0;
        if (e < elim) {
            int s = edge_at(ei, is64, e);
            int d = edge_at(ei, is64, (long long)NE + e);
            if ((unsigned)s < NN && (unsigned)d < NN) {
                bk = d >> 8;
                rc = (unsigned)s | ((unsigned)(d & 255) << 17);
                atomicAdd(&cnt[bk], 1);
            }
        }
        recs[j] = rc; bkts[j] = bk;
    }
    __syncthreads();
    excl[t] = cnt[t]; excl[t + 256] = cnt[t + 256];
    __syncthreads();
    for (int off = 1; off < 512; off <<= 1) {
        int a0 = (t >= off) ? excl[t - off] : 0;
        int a1 = (t + 256 >= off) ? excl[t + 256 - off] : 0;
        __syncthreads();
        excl[t] += a0; excl[t + 256] += a1;
        __syncthreads();
    }
    int i0 = excl[t] - cnt[t], i1 = excl[t + 256] - cnt[t + 256];
    excl[t] = i0; excl[t + 256] = i1;
    cur[t] = i0; cur[t + 256] = i1;
    for (int b = t; b < NBUK; b += 256) gbase[b] = scanned[(size_t)b * NCHK + blk];
    __syncthreads();
#pragma unroll
    for (int j = 0; j < EPT; j++) {
        if (bkts[j] >= 0) {
            int pos = atomicAdd(&cur[bkts[j]], 1);
            lbuf[pos] = recs[j];
            lbkt[pos] = (unsigned short)bkts[j];
        }
    }
    __syncthreads();
    const int tot = excl[NBUK];
    for (int i = t; i < tot; i += 256) {
        int b = lbkt[i];
        staging[(size_t)gbase[b] + (i - excl[b])] = lbuf[i];
    }
}

// ---------------- CSR build: pass 3, per-bucket deg/row_off/dinv + sorted csr ----------------
__global__ __launch_bounds__(256) void k_phaseB2(const unsigned* __restrict__ staging,
                                                 const int* __restrict__ scanned,
                                                 float* __restrict__ dinv,
                                                 int* __restrict__ row_off,
                                                 int* __restrict__ csr) {
    __shared__ int cnt[256], excl[256], cur[256];
    __shared__ int buf[8192];
    const int t = threadIdx.x, b = blockIdx.x;
    const int node0 = b << 8;
    const int nlocal = min(256, NN - node0);
    const int seg_beg = scanned[(size_t)b * NCHK];
    const size_t nxt = (size_t)(b + 1) * NCHK;
    const int seg_end = scanned[nxt > (size_t)LCNT ? (size_t)LCNT : nxt];
    const int len = min(seg_end - seg_beg, 8192);
    cnt[t] = 0;
    __syncthreads();
    for (int i = t; i < len; i += 256) {
        unsigned r = staging[seg_beg + i];
        atomicAdd(&cnt[r >> 17], 1);
    }
    __syncthreads();
    excl[t] = cnt[t];
    __syncthreads();
    for (int off = 1; off < 256; off <<= 1) {
        int x = (t >= off) ? excl[t - off] : 0;
        __syncthreads();
        excl[t] += x;
        __syncthreads();
    }
    int ex = excl[t] - cnt[t];
    excl[t] = ex;
    cur[t] = ex;
    if (t < nlocal) {
        row_off[node0 + t] = seg_beg + ex;
        dinv[node0 + t] = rsqrtf((float)(cnt[t] + 1));  // +1 self loop
    }
    if (b == NBUK - 1 && t == 0) row_off[NN] = seg_end;
    __syncthreads();
    for (int i = t; i < len; i += 256) {
        unsigned r = staging[seg_beg + i];
        int pos = atomicAdd(&cur[r >> 17], 1);
        buf[pos] = (int)(r & 0x1FFFFu);
    }
    __syncthreads();
    for (int i = t; i < len; i += 256) csr[seg_beg + i] = buf[i];
}

// ---------------- W pack: f32 W[k][n] -> f16 frag array P[((kc*NT+ct)*64+lane)*8+j] ----
// k = kc*32 + (lane>>4)*8 + j, n = ct*16 + (lane&15). Same (lane,j)->k map as A-frags:
// any consistent bijection over k is valid (MFMA pairs A/B slots positionally).
template <int C>
__global__ void k_packW(const float* __restrict__ W, _Float16* __restrict__ P) {
    constexpr int NT = C / 16;
    int i = blockIdx.x * 256 + threadIdx.x;
    if (i >= 4 * NT * 512) return;
    int j = i & 7, lane = (i >> 3) & 63;
    int rest = i >> 9;
    int ct = rest % NT, kc = rest / NT;
    int k = kc * 32 + (lane >> 4) * 8 + j;
    int n = ct * 16 + (lane & 15);
    P[i] = (_Float16)W[k * C + n];
}

// ---------------- MFMA GEMM: Hf16[n,:] = f16(dinv[n] * (X[n,:] @ W)) ----------------
// Block = 4 waves x 16 rows = 64 rows, full C cols. No LDS.
template <int C, bool F32SRC>
__global__ __launch_bounds__(256) void k_mgemm(const void* __restrict__ Xv,
                                               const _Float16* __restrict__ P,
                                               const float* __restrict__ dinv,
                                               unsigned short* __restrict__ H) {
    constexpr int NT = C / 16;
    const int tid = threadIdx.x, w = tid >> 6, lane = tid & 63;
    const int lr = lane & 15, lg = lane >> 4;
    const int row = blockIdx.x * 64 + w * 16 + lr;         // A row this lane loads
    const int arow = F32SRC ? min(row, NN - 1) : row;      // x input is not padded
    f32x4 acc[NT];
#pragma unroll
    for (int t = 0; t < NT; t++) acc[t] = (f32x4){0.f, 0.f, 0.f, 0.f};
    const f16x8* __restrict__ Pp = (const f16x8*)P;
#pragma unroll
    for (int kc = 0; kc < 4; kc++) {
        f16x8 a;
        if (F32SRC) {
            const float* xp = (const float*)Xv + (size_t)arow * 128 + kc * 32 + lg * 8;
            float4 x0 = *(const float4*)xp;
            float4 x1 = *(const float4*)(xp + 4);
            a[0] = (_Float16)x0.x; a[1] = (_Float16)x0.y;
            a[2] = (_Float16)x0.z; a[3] = (_Float16)x0.w;
            a[4] = (_Float16)x1.x; a[5] = (_Float16)x1.y;
            a[6] = (_Float16)x1.z; a[7] = (_Float16)x1.w;
        } else {
            a = *(const f16x8*)((const _Float16*)Xv + (size_t)arow * 128 + kc * 32 + lg * 8);
        }
#pragma unroll
        for (int t = 0; t < NT; t++) {
            f16x8 b = Pp[(kc * NT + t) * 64 + lane];
            acc[t] = __builtin_amdgcn_mfma_f32_16x16x32_f16(a, b, acc[t], 0, 0, 0);
        }
    }
    // D mapping: col = lane&15, row_in_tile = (lane>>4)*4 + reg  [HW-verified]
    const int orow0 = blockIdx.x * 64 + w * 16 + lg * 4;
    float dv[4];
#pragma unroll
    for (int r = 0; r < 4; r++) dv[r] = dinv[orow0 + r];
#pragma unroll
    for (int t = 0; t < NT; t++)
#pragma unroll
        for (int r = 0; r < 4; r++)
            H[(size_t)(orow0 + r) * C + t * 16 + lr] = f2h(acc[t][r] * dv[r]);
}

// ---------------- Aggregation C=128 (f16 H): 2 nodes/wave, f16 out ----------------
template <bool RELU>
__global__ __launch_bounds__(256) void k_agg128(const unsigned short* __restrict__ H,
                                                const int* __restrict__ row_off,
                                                const int* __restrict__ csr,
                                                const float* __restrict__ dinv,
                                                const float* __restrict__ bias,
                                                unsigned short* __restrict__ OUT) {
    const int tid = threadIdx.x;
    const int wid = tid >> 6, lane = tid & 63;
    const int half = lane >> 5, il = lane & 31;
    const int node = blockIdx.x * 8 + wid * 2 + half;  // NN = 12500*8 exactly
    const int beg = row_off[node];
    const int cnt = row_off[node + 1] - beg;
    const int tmax = max(cnt, __shfl(cnt, lane ^ 32));
    const ushort4* __restrict__ Hh = (const ushort4*)H;  // 32 ushort4 per row
    float4 acc = make_float4(0.f, 0.f, 0.f, 0.f);
    for (int j0 = 0; j0 < tmax; j0 += 32) {
        int sidx = node;
        if (j0 + il < cnt) sidx = csr[beg + j0 + il];
        const int rem = min(32, tmax - j0);
        for (int u = 0; u < rem; u += 8) {
            ushort4 v[8]; float m[8];
#pragma unroll
            for (int k = 0; k < 8; k++) {
                int s = __shfl(sidx, half * 32 + u + k);
                v[k] = Hh[(size_t)s * 32 + il];
                m[k] = (j0 + u + k < cnt) ? 1.f : 0.f;
            }
#pragma unroll
            for (int k = 0; k < 8; k++) {
                acc.x = fmaf(m[k], h2f(v[k].x), acc.x);
                acc.y = fmaf(m[k], h2f(v[k].y), acc.y);
                acc.z = fmaf(m[k], h2f(v[k].z), acc.z);
                acc.w = fmaf(m[k], h2f(v[k].w), acc.w);
            }
        }
    }
    ushort4 hv = Hh[(size_t)node * 32 + il];
    acc.x += h2f(hv.x); acc.y += h2f(hv.y);
    acc.z += h2f(hv.z); acc.w += h2f(hv.w);
    const float dv = dinv[node];
    float4 bb = ((const float4*)bias)[il];
    float ox = fmaf(acc.x, dv, bb.x), oy = fmaf(acc.y, dv, bb.y);
    float oz = fmaf(acc.z, dv, bb.z), ow = fmaf(acc.w, dv, bb.w);
    if (RELU) {
        ox = fmaxf(ox, 0.f); oy = fmaxf(oy, 0.f);
        oz = fmaxf(oz, 0.f); ow = fmaxf(ow, 0.f);
    }
    ushort4 oh;
    oh.x = f2h(ox); oh.y = f2h(oy); oh.z = f2h(oz); oh.w = f2h(ow);
    ((ushort4*)OUT)[(size_t)node * 32 + il] = oh;
}

// ---------------- Aggregation C=64 (f16 H): 4 nodes/wave, f32 out ----------------
__global__ __launch_bounds__(256) void k_agg64(const unsigned short* __restrict__ H,
                                               const int* __restrict__ row_off,
                                               const int* __restrict__ csr,
                                               const float* __restrict__ dinv,
                                               const float* __restrict__ bias,
                                               float* __restrict__ OUT) {
    const int tid = threadIdx.x;
    const int wid = tid >> 6, lane = tid & 63;
    const int q = lane >> 4, il = lane & 15;
    const int node = blockIdx.x * 16 + wid * 4 + q;  // NN = 6250*16 exactly
    const int beg = row_off[node];
    const int cnt = row_off[node + 1] - beg;
    int m1 = max(cnt, __shfl(cnt, lane ^ 16));
    const int tmax = max(m1, __shfl(m1, lane ^ 32));
    const ushort4* __restrict__ Hh = (const ushort4*)H;  // 16 ushort4 per row
    float4 acc = make_float4(0.f, 0.f, 0.f, 0.f);
    for (int j0 = 0; j0 < tmax; j0 += 16) {
        int sidx = node;
        if (j0 + il < cnt) sidx = csr[beg + j0 + il];
        const int rem = min(16, tmax - j0);
        for (int u = 0; u < rem; u += 8) {
            ushort4 v[8]; float m[8];
#pragma unroll
            for (int k = 0; k < 8; k++) {
                int s = __shfl(sidx, q * 16 + u + k);
                v[k] = Hh[(size_t)s * 16 + il];
                m[k] = (j0 + u + k < cnt) ? 1.f : 0.f;
            }
#pragma unroll
            for (int k = 0; k < 8; k++) {
                acc.x = fmaf(m[k], h2f(v[k].x), acc.x);
                acc.y = fmaf(m[k], h2f(v[k].y), acc.y);
                acc.z = fmaf(m[k], h2f(v[k].z), acc.z);
                acc.w = fmaf(m[k], h2f(v[k].w), acc.w);
            }
        }
    }
    ushort4 hv = Hh[(size_t)node * 16 + il];
    acc.x += h2f(hv.x); acc.y += h2f(hv.y);
    acc.z += h2f(hv.z); acc.w += h2f(hv.w);
    const float dv = dinv[node];
    float4 bb = ((const float4*)bias)[il];
    float4 o;
    o.x = fmaf(acc.x, dv, bb.x); o.y = fmaf(acc.y, dv, bb.y);
    o.z = fmaf(acc.z, dv, bb.z); o.w = fmaf(acc.w, dv, bb.w);
    ((float4*)OUT)[(size_t)node * 16 + il] = o;
}

extern "C" void kernel_launch(void* const* d_in, const int* in_sizes, int n_in,
                              void* d_out, int out_size, void* d_ws, size_t ws_size,
                              hipStream_t stream) {
    const float* x  = (const float*)d_in[0];
    const void*  ei = d_in[1];
    const float* W1 = (const float*)d_in[2];
    const float* b1 = (const float*)d_in[3];
    const float* W2 = (const float*)d_in[4];
    const float* b2 = (const float*)d_in[5];
    const float* W3 = (const float*)d_in[6];
    const float* b3 = (const float*)d_in[7];
    float* out = (float*)d_out;

    char* wsp = (char*)d_ws;
    size_t off = 0;
    auto alloc = [&](size_t bytes) -> void* {
        void* p = wsp + off;
        off += (bytes + 255) & ~(size_t)255;
        return p;
    };
    unsigned short* G = (unsigned short*)alloc((size_t)NN_PAD * 128 * 2);  // GEMM out (f16)
    unsigned short* F = (unsigned short*)alloc((size_t)NN_PAD * 128 * 2);  // agg out (f16)
    float* dinv    = (float*)alloc((size_t)NN_PAD * 4);
    int*   row_off = (int*)alloc(((size_t)NN + 1) * 4);
    int*   counts  = (int*)alloc(((size_t)LCNT + 1) * 4);
    int*   bsum    = (int*)alloc(((size_t)SCB + 1) * 4);
    int*   csr     = (int*)alloc((size_t)NE * 4);
    _Float16* P1   = (_Float16*)alloc((size_t)128 * 128 * 2);
    _Float16* P2   = (_Float16*)alloc((size_t)128 * 128 * 2);
    _Float16* P3   = (_Float16*)alloc((size_t)128 * 64 * 2);
    int*   flag    = (int*)alloc(256);
    if (off > ws_size) return;

    unsigned* staging = (unsigned*)G;  // aliases G (dead until gemm layer 1)

    k_detect_i64<<<1, 256, 0, stream>>>((const unsigned*)ei, flag);
    k_count<<<NCHK, 256, 0, stream>>>(ei, flag, counts);
    k_scan1v<<<SCB, 256, 0, stream>>>(counts, bsum);
    k_scan2v<<<1, 256, 0, stream>>>(bsum);
    k_scan3v<<<(LCNT + 1 + 255) / 256, 256, 0, stream>>>(counts, bsum);
    k_scatter2<<<NCHK, 256, 0, stream>>>(ei, flag, counts, staging);
    k_phaseB2<<<NBUK, 256, 0, stream>>>(staging, counts, dinv, row_off, csr);

    k_packW<128><<<64, 256, 0, stream>>>(W1, P1);
    k_packW<128><<<64, 256, 0, stream>>>(W2, P2);
    k_packW<64><<<32, 256, 0, stream>>>(W3, P3);

    constexpr int NBLK = NN_PAD / 64;  // 1563
    k_mgemm<128, true><<<NBLK, 256, 0, stream>>>(x, P1, dinv, G);
    k_agg128<true><<<NN / 8, 256, 0, stream>>>(G, row_off, csr, dinv, b1, F);
    k_mgemm<128, false><<<NBLK, 256, 0, stream>>>(F, P2, dinv, G);
    k_agg128<true><<<NN / 8, 256, 0, stream>>>(G, row_off, csr, dinv, b2, F);
    k_mgemm<64, false><<<NBLK, 256, 0, stream>>>(F, P3, dinv, G);
    k_agg64<<<NN / 16, 256, 0, stream>>>(G, row_off, csr, dinv, b3, out);
}